// Round 12
// baseline (882.408 us; speedup 1.0000x reference)
//
#include <hip/hip_runtime.h>

// OT Sinkhorn loss. B=4 images, N=1024 pts, 128x128 grid, 100 iters.
// R12 = R11 (slack-poll sync, fused init, strict tail) + REGISTER-RESIDENT
// phase A: per-thread entries packed {K17|flag|sub2|slot10} in <=32 VGPRs
// (constant across iters; only u changes). u_lds loads become independent
// register-addressed -> pipelined, killing the ~22-deep dependent-LDS
// chain that R11 showed is the 5.4us/iter floor (slack poll changed
// nothing vs strict -> sync was NOT the cost). Overflow -> LDS CSR walk.

#define GRID_N 128
#define NCELL  16384
#define NPTS   1024
#define NIMG   4
#define NITER  100
#define STRICT_AT 94
#define SLACK  4
#define NBAND  16
#define TPB    512
#define VROWS  14
#define VCELLS (VROWS*GRID_N)   // 1792
#define ENT_CAP 12288
#define CPT 4                   // cells/thread in scan
#define MAXE 32                 // register entries/thread (Poisson(12), P(>32)~1e-7)

#define C2   (-0.14426950408889634f)   // -log2(e)/10
#define EPSF 1e-16f
#define AGENT __HIP_MEMORY_SCOPE_AGENT

// ws: [0..16) loss f32[4]; [16..20) done; [20..24) gate; [64..) u2 stamps
#define WS_U_B   64
#define WS_TOTAL (WS_U_B + NIMG*2*NPTS*8)
#define ZERO_BYTES WS_TOTAL

__device__ __forceinline__ void window_of(float px, float py, int& r_lo, int& c_lo)
{
    int kc = (int)(px * 0.125f); kc = kc < 0 ? 0 : (kc > GRID_N-1 ? GRID_N-1 : kc);
    int kr = (int)(py * 0.125f); kr = kr < 0 ? 0 : (kr > GRID_N-1 ? GRID_N-1 : kr);
    c_lo = kc - 3; c_lo = c_lo < 0 ? 0 : (c_lo > GRID_N-7 ? GRID_N-7 : c_lo);
    r_lo = kr - 3; r_lo = r_lo < 0 ? 0 : (r_lo > GRID_N-7 ? GRID_N-7 : r_lo);
}

__device__ __forceinline__ float poll_u2(const unsigned long long* addr, int target)
{
    unsigned long long w = __hip_atomic_load(addr, __ATOMIC_RELAXED, AGENT);
    int spins = 0;
    while ((int)(unsigned)(w >> 32) < target) {
        __builtin_amdgcn_s_sleep(1);
        w = __hip_atomic_load(addr, __ATOMIC_RELAXED, AGENT);
        if (++spins > (1<<22)) break;   // monotone stamp => unreachable
    }
    return __uint_as_float((unsigned)w);
}

__global__ __launch_bounds__(TPB) void ot_main_kernel(
    const float* __restrict__ dens, const float* __restrict__ pts,
    unsigned* __restrict__ ws_u32, float* __restrict__ out)
{
    const int img = (int)blockIdx.x >> 4, bnd = (int)blockIdx.x & 15;
    const int t = threadIdx.x;
    float* ws_f = (float*)ws_u32;
    unsigned long long* u2_g =
        (unsigned long long*)((char*)ws_u32 + WS_U_B) + img*2*NPTS;

    __shared__ float    vbuf[VCELLS];      // v (aliased cnt during build)
    __shared__ float    densV[VCELLS];
    __shared__ unsigned offs[VCELLS + 1];
    __shared__ unsigned ent[ENT_CAP];      // {K22 | slot10} (overflow path)
    __shared__ float    u_lds[NPTS];       // slot-indexed
    __shared__ float    px_l[NPTS], py_l[NPTS];
    __shared__ unsigned keys_s[NPTS];
    __shared__ unsigned bofs[17];
    __shared__ unsigned cnt16[16];
    __shared__ unsigned swsum[9];
    __shared__ float    red[8];

    const int v1lo = (bnd*8-3) < 0 ? 0 : (bnd*8-3);
    const int v1hi = (bnd*8+10) > 127 ? 127 : (bnd*8+10);
    const int cells = (v1hi - v1lo + 1) * GRID_N;
    const float A = 1.0f / (float)NPTS;

    unsigned* cnt = (unsigned*)vbuf;       // alias during build only

    // ---- init 1: load pts, keys, band histogram ----
    float mpx[2], mpy[2]; int mband[2]; unsigned mkey[2];
#pragma unroll
    for (int j = 0; j < 2; ++j) {
        int p = t + j*TPB;
        mpx[j] = pts[(img*NPTS + p)*2 + 0];
        mpy[j] = pts[(img*NPTS + p)*2 + 1];
        int kr = (int)(mpy[j] * 0.125f); kr = kr < 0 ? 0 : (kr > 127 ? 127 : kr);
        mband[j] = kr >> 3;
        mkey[j] = ((unsigned)mband[j] << 10) | (unsigned)p;
        keys_s[p] = mkey[j];
    }
    if (t < 16) cnt16[t] = 0;
    __syncthreads();
#pragma unroll
    for (int j = 0; j < 2; ++j) atomicAdd(&cnt16[mband[j]], 1u);
    __syncthreads();
    if (t == 0) {
        unsigned run = 0;
        for (int i = 0; i < 16; ++i) { bofs[i] = run; run += cnt16[i]; }
        bofs[16] = run;
    }
    __syncthreads();

    // ---- init 2: deterministic rank sort (key = band<<10 | pid) ----
    {
        int r0 = 0, r1 = 0;
        for (int q = 0; q < NPTS; ++q) {
            unsigned kq = keys_s[q];
            r0 += (kq < mkey[0]); r1 += (kq < mkey[1]);
        }
        px_l[r0] = mpx[0]; py_l[r0] = mpy[0]; u_lds[r0] = A;
        px_l[r1] = mpx[1]; py_l[r1] = mpy[1]; u_lds[r1] = A;
    }
    __syncthreads();

    // ---- init 3: densV + zero cnt ----
    for (int i = t; i < cells; i += TPB) {
        densV[i] = dens[img*NCELL + v1lo*GRID_N + i];
        cnt[i] = 0u;
    }
    const int s0 = (int)bofs[bnd > 0 ? bnd-1 : 0];
    const int s1 = (int)bofs[(bnd < 15 ? bnd+1 : 15) + 1];
    const int p0 = (int)bofs[bnd];
    const int pn = (int)bofs[bnd+1] - p0;
    __syncthreads();

    // ---- init 4: local CSR count (points of bands b-1..b+1) ----
    for (int i = s0 + t; i < s1; i += TPB) {
        int r_lo, c_lo; window_of(px_l[i], py_l[i], r_lo, c_lo);
#pragma unroll
        for (int wy = 0; wy < 7; ++wy) {
            int row = r_lo + wy;
            if (row >= v1lo && row <= v1hi) {
                int base = (row - v1lo)*GRID_N + c_lo;
#pragma unroll
                for (int wx = 0; wx < 7; ++wx) atomicAdd(&cnt[base + wx], 1u);
            }
        }
    }
    __syncthreads();

    // ---- init 5: exclusive scan cnt -> offs ----
    {
        const int c0 = t*CPT;
        unsigned lc[CPT]; unsigned csum = 0;
#pragma unroll
        for (int k = 0; k < CPT; ++k) {
            int ci = c0 + k;
            lc[k] = (ci < cells) ? cnt[ci] : 0u;
            csum += lc[k];
        }
        unsigned inc = csum;
        const int lane = t & 63;
#pragma unroll
        for (int d = 1; d < 64; d <<= 1) {
            unsigned x = __shfl_up(inc, d, 64);
            if (lane >= d) inc += x;
        }
        if (lane == 63) swsum[t >> 6] = inc;
        __syncthreads();
        if (t < 8) {
            unsigned wv = swsum[t], winc = wv;
#pragma unroll
            for (int d = 1; d < 8; d <<= 1) {
                unsigned x = __shfl_up(winc, d, 8);
                if (t >= d) winc += x;
            }
            swsum[t] = winc - wv;
            if (t == 7) swsum[8] = winc;
        }
        __syncthreads();
        unsigned run = swsum[t >> 6] + (inc - csum);
#pragma unroll
        for (int k = 0; k < CPT; ++k) {
            int ci = c0 + k;
            if (ci < cells) { offs[ci] = run; run += lc[k]; }
        }
        if (t == 0) offs[cells] = swsum[8];
    }
    __syncthreads();

    // ---- init 6: CSR fill {K22|slot10} (drains cnt) ----
    for (int i = s0 + t; i < s1; i += TPB) {
        float px = px_l[i], py = py_l[i];
        int r_lo, c_lo; window_of(px, py, r_lo, c_lo);
#pragma unroll
        for (int wy = 0; wy < 7; ++wy) {
            int row = r_lo + wy;
            if (row >= v1lo && row <= v1hi) {
                float dy = py - (float)(8*row + 4);
                int base = (row - v1lo)*GRID_N + c_lo;
#pragma unroll
                for (int wx = 0; wx < 7; ++wx) {
                    float dx = px - (float)(8*(c_lo+wx) + 4);
                    float K = exp2f(C2 * (dx*dx + dy*dy));
                    unsigned e = ((__float_as_uint(K) + 0x200u) & 0xFFFFFC00u)
                               | (unsigned)i;
                    unsigned old = atomicSub(&cnt[base + wx], 1u);
                    unsigned idx = offs[base + wx] + old - 1u;
                    if (idx < ENT_CAP) ent[idx] = e;
                }
            }
        }
    }
    __syncthreads();

    // ---- init 6.5: per-thread register entry pack {K17|flag|sub2|slot10};
    //      preset v for zero-count cells (constant across iters) ----
    unsigned Ereg[MAXE];
    int myCnt = 0;
    bool ovf = false;
#pragma unroll
    for (int k = 0; k < 4; ++k) {
        int ci = t + k*TPB;
        if (ci < cells) {
            unsigned oA = offs[ci], oB = offs[ci+1];
            int cn = (int)(oB - oA);
            if (cn == 0) {
                vbuf[ci] = densV[ci] / EPSF;   // never touched again
            } else if (!ovf && myCnt + cn <= MAXE && oB <= ENT_CAP) {
                for (int e = 0; e < cn; ++e) {
                    unsigned E = ent[oA + e];
                    unsigned K17 = ((E & 0xFFFFFC00u) + 0x4000u) & 0xFFFF8000u;
                    unsigned fl  = (e == cn-1) ? 0x4000u : 0u;
                    Ereg[myCnt++] = K17 | fl | ((unsigned)k << 10) | (E & 0x3FFu);
                }
            } else {
                ovf = true;                    // fall back to LDS walk
            }
        }
    }
#pragma unroll
    for (int j = 0; j < MAXE; ++j) if (j >= myCnt) Ereg[j] = 0u;
    if (ovf) myCnt = 0;

    // ---- init 7: prestored K for own points (4 threads/point) ----
    const int sub = t & 3, idx4 = t >> 2;
    int km = 0;
    float Kq[13], Kd2[13]; int cq[13];
    if (idx4 < pn && idx4 < 128) {
        float px = px_l[p0 + idx4], py = py_l[p0 + idx4];
        int r_lo, c_lo; window_of(px, py, r_lo, c_lo);
        int k = 0;
#pragma unroll
        for (int q = 0; q < 49; ++q) {
            if ((q & 3) == sub) {
                int wy = q / 7, wx = q % 7;
                float dx = px - (float)(8*(c_lo+wx) + 4);
                float dy = py - (float)(8*(r_lo+wy) + 4);
                float d2 = dx*dx + dy*dy;
                float K = exp2f(C2 * d2);
                Kq[k] = K; Kd2[k] = K * d2;
                cq[k] = (r_lo + wy - v1lo)*GRID_N + (c_lo + wx);
                ++k;
            }
        }
        km = k;
    }

    // ---- init 8: seed both parity buffers with {stamp0, A}; global gate ----
    for (int i = p0 + t; i < p0 + pn; i += TPB) {
        unsigned long long seed = (unsigned long long)__float_as_uint(A);
        __hip_atomic_store(u2_g + i,        seed, __ATOMIC_RELAXED, AGENT);
        __hip_atomic_store(u2_g + NPTS + i, seed, __ATOMIC_RELAXED, AGENT);
    }
    __syncthreads();
    if (t == 0) {
        __hip_atomic_fetch_add(ws_u32 + 5, 1u, __ATOMIC_ACQ_REL, AGENT);
        int spins = 0;
        while (__hip_atomic_load(ws_u32 + 5, __ATOMIC_ACQUIRE, AGENT)
               < (unsigned)(NIMG*NBAND)) {
            __builtin_amdgcn_s_sleep(2);
            if (++spins > (1<<22)) break;
        }
    }
    __syncthreads();

    float li_acc = 0.f;

    // ============ iteration loop: slack poll 0..93, strict 94..99 ============
    for (int it = 0; it < NITER; ++it) {
        if (it > 0) {
            const unsigned long long* src = u2_g + (unsigned)((it-1) & 1)*NPTS;
            const int tgt = (it >= STRICT_AT) ? it
                          : (it > SLACK ? it - SLACK : 0);
            for (int i = s0 + t; i < p0; i += TPB)
                u_lds[i] = poll_u2(src + i, tgt);
            for (int i = p0 + pn + t; i < s1; i += TPB)
                u_lds[i] = poll_u2(src + i, tgt);
        }
        __syncthreads();

        // ---- phase A: v = b/(K^T u + eps) -- register entries, u loads
        //      independent (register-known addresses) ----
        if (!ovf) {
            float s = 0.f;
#pragma unroll
            for (int j = 0; j < MAXE; ++j) {
                if (j < myCnt) {
                    unsigned e = Ereg[j];
                    s = fmaf(__uint_as_float(e & 0xFFFF8000u),
                             u_lds[e & 0x3FFu], s);
                    if (e & 0x4000u) {
                        int ci = t + (int)((e >> 10) & 3u)*TPB;
                        vbuf[ci] = densV[ci] / (s + EPSF);
                        s = 0.f;
                    }
                }
            }
        } else {
            // rare: LDS CSR walk (R11 path)
#pragma unroll
            for (int k = 0; k < 4; ++k) {
                int ci = t + k*TPB;
                if (ci < cells) {
                    unsigned oA = offs[ci];
                    unsigned oB = offs[ci+1]; if (oB > ENT_CAP) oB = ENT_CAP;
                    if (oB > oA) {
                        float s = 0.f;
                        for (unsigned e = oA; e < oB; ++e) {
                            unsigned E = ent[e];
                            s = fmaf(__uint_as_float(E & 0xFFFFFC00u),
                                     u_lds[E & 0x3FFu], s);
                        }
                        vbuf[ci] = densV[ci] / (s + EPSF);
                    }
                }
            }
        }
        __syncthreads();

        // ---- phase B: u = A / (K v + eps); publish stamped ----
        unsigned long long* dst = u2_g + (unsigned)(it & 1)*NPTS;
        const unsigned long long hs = ((unsigned long long)(unsigned)(it+1)) << 32;
        const bool last = (it == NITER-1);
        if (idx4 < pn && idx4 < 128) {
            float kv = 0.f, kd = 0.f;
#pragma unroll
            for (int k = 0; k < 13; ++k) {
                if (k < km) {
                    float vj = vbuf[cq[k]];
                    kv = fmaf(Kq[k],  vj, kv);
                    kd = fmaf(Kd2[k], vj, kd);
                }
            }
            kv += __shfl_xor(kv, 1); kv += __shfl_xor(kv, 2);
            float u_new = A / (kv + EPSF);
            if (sub == 0) {
                u_lds[p0 + idx4] = u_new;
                __hip_atomic_store(dst + p0 + idx4,
                                   hs | __float_as_uint(u_new),
                                   __ATOMIC_RELAXED, AGENT);
            }
            if (last) {
                kd += __shfl_xor(kd, 1); kd += __shfl_xor(kd, 2);
                if (sub == 0) li_acc += u_new * kd;
            }
        }
        for (int b2 = 128; b2 < pn; b2 += 128) {   // rare overflow
            int i2 = b2 + idx4;
            if (i2 < pn) {
                int sl = p0 + i2;
                float px = px_l[sl], py = py_l[sl];
                int r_lo, c_lo; window_of(px, py, r_lo, c_lo);
                float kv = 0.f, kd = 0.f;
                for (int q = sub; q < 49; q += 4) {
                    int wy = q / 7, wx = q % 7;
                    float dx = px - (float)(8*(c_lo+wx) + 4);
                    float dy = py - (float)(8*(r_lo+wy) + 4);
                    float d2 = dx*dx + dy*dy;
                    float K = exp2f(C2 * d2);
                    float vj = vbuf[(r_lo + wy - v1lo)*GRID_N + c_lo + wx];
                    kv = fmaf(K, vj, kv); kd = fmaf(K*d2, vj, kd);
                }
                kv += __shfl_xor(kv, 1); kv += __shfl_xor(kv, 2);
                float u_new = A / (kv + EPSF);
                if (sub == 0) {
                    u_lds[sl] = u_new;
                    __hip_atomic_store(dst + sl, hs | __float_as_uint(u_new),
                                       __ATOMIC_RELAXED, AGENT);
                }
                if (last) {
                    kd += __shfl_xor(kd, 1); kd += __shfl_xor(kd, 2);
                    if (sub == 0) li_acc += u_new * kd;
                }
            }
        }
        __syncthreads();
    }

    // ---- loss reduction + last-WG finalize ----
#pragma unroll
    for (int o = 32; o > 0; o >>= 1) li_acc += __shfl_down(li_acc, o);
    if ((t & 63) == 0) red[t >> 6] = li_acc;
    __syncthreads();
    if (t == 0) {
        float s = 0.f;
#pragma unroll
        for (int w = 0; w < 8; ++w) s += red[w];
        atomicAdd(&ws_f[img], s);
        unsigned done = __hip_atomic_fetch_add(ws_u32 + 4, 1u,
                                               __ATOMIC_ACQ_REL, AGENT);
        if (done == (unsigned)(NIMG*NBAND - 1)) {
            float tot = 0.f;
#pragma unroll
            for (int i = 0; i < 4; ++i)
                tot += __hip_atomic_load(ws_f + i, __ATOMIC_RELAXED, AGENT);
            out[0] = tot;
            out[1] = tot;
            out[2] = 0.f;
        }
    }
}

// ---- fallback (ws too small): R1-verified single-kernel path ----
__global__ __launch_bounds__(1024) void ot_fallback_kernel(
    const float* __restrict__ dens, const float* __restrict__ pts,
    float* __restrict__ out)
{
    const int img = blockIdx.x, t = threadIdx.x;
    __shared__ float sv[NCELL];
    __shared__ float redf[16];

    const float px = pts[(size_t)img*NPTS*2 + t*2 + 0];
    const float py = pts[(size_t)img*NPTS*2 + t*2 + 1];
    int r_lo, c_lo; window_of(px, py, r_lo, c_lo);

    float dx2[7], dy2[7];
#pragma unroll
    for (int j = 0; j < 7; ++j) {
        float dx = px - (float)(8*(c_lo+j) + 4);
        float dy = py - (float)(8*(r_lo+j) + 4);
        dx2[j] = dx*dx; dy2[j] = dy*dy;
    }
    float K[49];
#pragma unroll
    for (int wy = 0; wy < 7; ++wy)
#pragma unroll
        for (int wx = 0; wx < 7; ++wx)
            K[wy*7+wx] = exp2f(C2 * (dx2[wx] + dy2[wy]));

    const int lbase = r_lo*GRID_N + c_lo;
    float breg[16];
    const float4* d4 = (const float4*)(dens + (size_t)img*NCELL + t*16);
#pragma unroll
    for (int j = 0; j < 4; ++j) {
        float4 v = d4[j];
        breg[j*4+0]=v.x; breg[j*4+1]=v.y; breg[j*4+2]=v.z; breg[j*4+3]=v.w;
    }
    const float A = 1.0f/(float)NPTS;
    float u = A;
    float4* sv4 = (float4*)sv;
    for (int it = 0; it < NITER; ++it) {
        __syncthreads();
#pragma unroll
        for (int j = 0; j < 4; ++j) sv4[t*4+j] = make_float4(0.f,0.f,0.f,0.f);
        __syncthreads();
#pragma unroll
        for (int wy = 0; wy < 7; ++wy)
#pragma unroll
            for (int wx = 0; wx < 7; ++wx)
                atomicAdd(&sv[lbase + wy*GRID_N + wx], u * K[wy*7+wx]);
        __syncthreads();
#pragma unroll
        for (int j = 0; j < 16; ++j) { int c = t*16+j; sv[c] = breg[j] / (sv[c] + EPSF); }
        __syncthreads();
        float kv = 0.f;
#pragma unroll
        for (int wy = 0; wy < 7; ++wy)
#pragma unroll
            for (int wx = 0; wx < 7; ++wx)
                kv = fmaf(K[wy*7+wx], sv[lbase + wy*GRID_N + wx], kv);
        u = A / (kv + EPSF);
    }
    float li = 0.f;
#pragma unroll
    for (int wy = 0; wy < 7; ++wy)
#pragma unroll
        for (int wx = 0; wx < 7; ++wx)
            li = fmaf(K[wy*7+wx] * (dx2[wx]+dy2[wy]), sv[lbase + wy*GRID_N + wx], li);
    li *= u;
#pragma unroll
    for (int o = 32; o > 0; o >>= 1) li += __shfl_down(li, o);
    if ((t & 63) == 0) redf[t >> 6] = li;
    __syncthreads();
    if (t == 0) {
        float s = 0.f;
#pragma unroll
        for (int w = 0; w < 16; ++w) s += redf[w];
        atomicAdd(&out[0], s);
        atomicAdd(&out[1], s);
    }
}

extern "C" void kernel_launch(void* const* d_in, const int* in_sizes, int n_in,
                              void* d_out, int out_size, void* d_ws, size_t ws_size,
                              hipStream_t stream)
{
    const float* dens = (const float*)d_in[0];   // [4,1,128,128]
    const float* pts  = (const float*)d_in[2];   // [4,1024,2]
    float* out = (float*)d_out;
    unsigned* ws_u32 = (unsigned*)d_ws;

    if (ws_size < (size_t)WS_TOTAL) {   // insurance: slow-but-correct path
        hipMemsetAsync(d_out, 0, 3*sizeof(float), stream);
        ot_fallback_kernel<<<NIMG, 1024, 0, stream>>>(dens, pts, out);
        return;
    }

    hipMemsetAsync(d_ws, 0, ZERO_BYTES, stream);   // loss+done+gate+u2
    ot_main_kernel<<<NIMG*NBAND, TPB, 0, stream>>>(dens, pts, ws_u32, out);
}

// Round 13
// 487.793 us; speedup vs baseline: 1.8090x; 1.8090x over previous
//
#include <hip/hip_runtime.h>

// OT Sinkhorn loss. B=4 images, N=1024 pts, 128x128 grid, 100 iters.
// R13 = R11 (best: slack-poll stamped sync, fused init, strict tail)
// + TPB 1024 (2x threads, 16 waves/CU: halves per-thread walk, hides
//   latency; same 1 WG/CU at 87KB LDS)
// + affine interleaved 2-cell phase-A walk (ent[a+k] affine addresses,
//   2-way ILP, chain = max not sum) -- R12's intent without its
//   32-step predicated-unroll pathology (R12 regressed 542->947us).

#define GRID_N 128
#define NCELL  16384
#define NPTS   1024
#define NIMG   4
#define NITER  100
#define STRICT_AT 94
#define SLACK  4
#define NBAND  16
#define TPB    1024
#define VROWS  14
#define VCELLS (VROWS*GRID_N)   // 1792
#define ENT_CAP 12288
#define CPT 2                   // cells/thread in scan (2*1024 >= 1792)

#define C2   (-0.14426950408889634f)   // -log2(e)/10
#define EPSF 1e-16f
#define AGENT __HIP_MEMORY_SCOPE_AGENT

// ws: [0..16) loss f32[4]; [16..20) done; [20..24) gate; [64..) u2 stamps
#define WS_U_B   64
#define WS_TOTAL (WS_U_B + NIMG*2*NPTS*8)
#define ZERO_BYTES WS_TOTAL

__device__ __forceinline__ void window_of(float px, float py, int& r_lo, int& c_lo)
{
    int kc = (int)(px * 0.125f); kc = kc < 0 ? 0 : (kc > GRID_N-1 ? GRID_N-1 : kc);
    int kr = (int)(py * 0.125f); kr = kr < 0 ? 0 : (kr > GRID_N-1 ? GRID_N-1 : kr);
    c_lo = kc - 3; c_lo = c_lo < 0 ? 0 : (c_lo > GRID_N-7 ? GRID_N-7 : c_lo);
    r_lo = kr - 3; r_lo = r_lo < 0 ? 0 : (r_lo > GRID_N-7 ? GRID_N-7 : r_lo);
}

__device__ __forceinline__ float poll_u2(const unsigned long long* addr, int target)
{
    unsigned long long w = __hip_atomic_load(addr, __ATOMIC_RELAXED, AGENT);
    int spins = 0;
    while ((int)(unsigned)(w >> 32) < target) {
        __builtin_amdgcn_s_sleep(1);
        w = __hip_atomic_load(addr, __ATOMIC_RELAXED, AGENT);
        if (++spins > (1<<22)) break;   // monotone stamp => unreachable
    }
    return __uint_as_float((unsigned)w);
}

__global__ __launch_bounds__(TPB) void ot_main_kernel(
    const float* __restrict__ dens, const float* __restrict__ pts,
    unsigned* __restrict__ ws_u32, float* __restrict__ out)
{
    const int img = (int)blockIdx.x >> 4, bnd = (int)blockIdx.x & 15;
    const int t = threadIdx.x;
    float* ws_f = (float*)ws_u32;
    unsigned long long* u2_g =
        (unsigned long long*)((char*)ws_u32 + WS_U_B) + img*2*NPTS;

    __shared__ float    vbuf[VCELLS];      // v (aliased cnt during build)
    __shared__ float    densV[VCELLS];
    __shared__ unsigned offs[VCELLS + 1];
    __shared__ unsigned ent[ENT_CAP];      // {K22 | slot10}
    __shared__ float    u_lds[NPTS];       // slot-indexed
    __shared__ float    px_l[NPTS], py_l[NPTS];
    __shared__ unsigned keys_s[NPTS];
    __shared__ unsigned bofs[17];
    __shared__ unsigned cnt16[16];
    __shared__ unsigned swsum[17];
    __shared__ float    red[16];

    const int v1lo = (bnd*8-3) < 0 ? 0 : (bnd*8-3);
    const int v1hi = (bnd*8+10) > 127 ? 127 : (bnd*8+10);
    const int cells = (v1hi - v1lo + 1) * GRID_N;
    const float A = 1.0f / (float)NPTS;

    unsigned* cnt = (unsigned*)vbuf;       // alias during build only

    // ---- init 1: load point, key, band histogram (1 pt/thread) ----
    const float mpx = pts[(img*NPTS + t)*2 + 0];
    const float mpy = pts[(img*NPTS + t)*2 + 1];
    int mkr = (int)(mpy * 0.125f); mkr = mkr < 0 ? 0 : (mkr > 127 ? 127 : mkr);
    const int mband = mkr >> 3;
    const unsigned mkey = ((unsigned)mband << 10) | (unsigned)t;
    keys_s[t] = mkey;
    if (t < 16) cnt16[t] = 0;
    __syncthreads();
    atomicAdd(&cnt16[mband], 1u);
    __syncthreads();
    if (t == 0) {
        unsigned run = 0;
        for (int i = 0; i < 16; ++i) { bofs[i] = run; run += cnt16[i]; }
        bofs[16] = run;
    }
    __syncthreads();

    // ---- init 2: deterministic rank sort (key = band<<10 | pid) ----
    {
        int r = 0;
        for (int q = 0; q < NPTS; ++q) r += (keys_s[q] < mkey);
        px_l[r] = mpx; py_l[r] = mpy; u_lds[r] = A;
    }
    __syncthreads();

    // ---- init 3: densV + zero cnt ----
    for (int i = t; i < cells; i += TPB) {
        densV[i] = dens[img*NCELL + v1lo*GRID_N + i];
        cnt[i] = 0u;
    }
    const int s0 = (int)bofs[bnd > 0 ? bnd-1 : 0];
    const int s1 = (int)bofs[(bnd < 15 ? bnd+1 : 15) + 1];
    const int p0 = (int)bofs[bnd];
    const int pn = (int)bofs[bnd+1] - p0;
    __syncthreads();

    // ---- init 4: local CSR count (points of bands b-1..b+1) ----
    for (int i = s0 + t; i < s1; i += TPB) {
        int r_lo, c_lo; window_of(px_l[i], py_l[i], r_lo, c_lo);
#pragma unroll
        for (int wy = 0; wy < 7; ++wy) {
            int row = r_lo + wy;
            if (row >= v1lo && row <= v1hi) {
                int base = (row - v1lo)*GRID_N + c_lo;
#pragma unroll
                for (int wx = 0; wx < 7; ++wx) atomicAdd(&cnt[base + wx], 1u);
            }
        }
    }
    __syncthreads();

    // ---- init 5: exclusive scan cnt -> offs (16-wave shfl scan) ----
    {
        const int c0 = t*CPT;
        unsigned lc[CPT]; unsigned csum = 0;
#pragma unroll
        for (int k = 0; k < CPT; ++k) {
            int ci = c0 + k;
            lc[k] = (ci < cells) ? cnt[ci] : 0u;
            csum += lc[k];
        }
        unsigned inc = csum;
        const int lane = t & 63;
#pragma unroll
        for (int d = 1; d < 64; d <<= 1) {
            unsigned x = __shfl_up(inc, d, 64);
            if (lane >= d) inc += x;
        }
        if (lane == 63) swsum[t >> 6] = inc;
        __syncthreads();
        if (t < 16) {
            unsigned wv = swsum[t], winc = wv;
#pragma unroll
            for (int d = 1; d < 16; d <<= 1) {
                unsigned x = __shfl_up(winc, d, 16);
                if (t >= d) winc += x;
            }
            swsum[t] = winc - wv;
            if (t == 15) swsum[16] = winc;
        }
        __syncthreads();
        unsigned run = swsum[t >> 6] + (inc - csum);
#pragma unroll
        for (int k = 0; k < CPT; ++k) {
            int ci = c0 + k;
            if (ci < cells) { offs[ci] = run; run += lc[k]; }
        }
        if (t == 0) offs[cells] = swsum[16];
    }
    __syncthreads();

    // ---- init 6: CSR fill {K22|slot10} (drains cnt) ----
    for (int i = s0 + t; i < s1; i += TPB) {
        float px = px_l[i], py = py_l[i];
        int r_lo, c_lo; window_of(px, py, r_lo, c_lo);
#pragma unroll
        for (int wy = 0; wy < 7; ++wy) {
            int row = r_lo + wy;
            if (row >= v1lo && row <= v1hi) {
                float dy = py - (float)(8*row + 4);
                int base = (row - v1lo)*GRID_N + c_lo;
#pragma unroll
                for (int wx = 0; wx < 7; ++wx) {
                    float dx = px - (float)(8*(c_lo+wx) + 4);
                    float K = exp2f(C2 * (dx*dx + dy*dy));
                    unsigned e = ((__float_as_uint(K) + 0x200u) & 0xFFFFFC00u)
                               | (unsigned)i;
                    unsigned old = atomicSub(&cnt[base + wx], 1u);
                    unsigned idx = offs[base + wx] + old - 1u;
                    if (idx < ENT_CAP) ent[idx] = e;
                }
            }
        }
    }
    __syncthreads();

    // ---- init 6.5: cell-side registers (2 cells/thread, stride TPB) ----
    const int ci0 = t, ci1 = t + TPB;
    const bool has1 = (ci1 < cells);
    unsigned ea0 = offs[ci0], eb0 = offs[ci0+1];
    if (eb0 > ENT_CAP) eb0 = ENT_CAP;
    if (ea0 > eb0) ea0 = eb0;
    const float dn0 = densV[ci0];
    unsigned ea1 = 0, eb1 = 0; float dn1 = 0.f;
    if (has1) {
        ea1 = offs[ci1]; eb1 = offs[ci1+1];
        if (eb1 > ENT_CAP) eb1 = ENT_CAP;
        if (ea1 > eb1) ea1 = eb1;
        dn1 = densV[ci1];
    }
    const unsigned n0 = eb0 - ea0, n1 = eb1 - ea1;
    const unsigned nmax = n0 > n1 ? n0 : n1;

    // ---- init 7: prestored K for own points (4 threads/point) ----
    const int sub = t & 3, idx4 = t >> 2;
    int km = 0;
    float Kq[13], Kd2[13]; int cq[13];
    if (idx4 < pn && idx4 < 256) {
        float px = px_l[p0 + idx4], py = py_l[p0 + idx4];
        int r_lo, c_lo; window_of(px, py, r_lo, c_lo);
        int k = 0;
#pragma unroll
        for (int q = 0; q < 49; ++q) {
            if ((q & 3) == sub) {
                int wy = q / 7, wx = q % 7;
                float dx = px - (float)(8*(c_lo+wx) + 4);
                float dy = py - (float)(8*(r_lo+wy) + 4);
                float d2 = dx*dx + dy*dy;
                float K = exp2f(C2 * d2);
                Kq[k] = K; Kd2[k] = K * d2;
                cq[k] = (r_lo + wy - v1lo)*GRID_N + (c_lo + wx);
                ++k;
            }
        }
        km = k;
    }

    // ---- init 8: seed both parity buffers with {stamp0, A}; global gate ----
    for (int i = p0 + t; i < p0 + pn; i += TPB) {
        unsigned long long seed = (unsigned long long)__float_as_uint(A);
        __hip_atomic_store(u2_g + i,        seed, __ATOMIC_RELAXED, AGENT);
        __hip_atomic_store(u2_g + NPTS + i, seed, __ATOMIC_RELAXED, AGENT);
    }
    __syncthreads();
    if (t == 0) {
        __hip_atomic_fetch_add(ws_u32 + 5, 1u, __ATOMIC_ACQ_REL, AGENT);
        int spins = 0;
        while (__hip_atomic_load(ws_u32 + 5, __ATOMIC_ACQUIRE, AGENT)
               < (unsigned)(NIMG*NBAND)) {
            __builtin_amdgcn_s_sleep(2);
            if (++spins > (1<<22)) break;
        }
    }
    __syncthreads();

    float li_acc = 0.f;

    // ============ iteration loop: slack poll 0..93, strict 94..99 ============
    for (int it = 0; it < NITER; ++it) {
        if (it > 0) {
            const unsigned long long* src = u2_g + (unsigned)((it-1) & 1)*NPTS;
            const int tgt = (it >= STRICT_AT) ? it
                          : (it > SLACK ? it - SLACK : 0);
            for (int i = s0 + t; i < p0; i += TPB)
                u_lds[i] = poll_u2(src + i, tgt);
            for (int i = p0 + pn + t; i < s1; i += TPB)
                u_lds[i] = poll_u2(src + i, tgt);
        }
        __syncthreads();

        // ---- phase A: interleaved affine 2-cell walk, 2-way ILP ----
        {
            float sum0 = 0.f, sum1 = 0.f;
            for (unsigned k = 0; k < nmax; ++k) {
                if (k < n0) {
                    unsigned E = ent[ea0 + k];
                    sum0 = fmaf(__uint_as_float(E & 0xFFFFFC00u),
                                u_lds[E & 0x3FFu], sum0);
                }
                if (k < n1) {
                    unsigned E = ent[ea1 + k];
                    sum1 = fmaf(__uint_as_float(E & 0xFFFFFC00u),
                                u_lds[E & 0x3FFu], sum1);
                }
            }
            vbuf[ci0] = dn0 / (sum0 + EPSF);
            if (has1) vbuf[ci1] = dn1 / (sum1 + EPSF);
        }
        __syncthreads();

        // ---- phase B: u = A / (K v + eps); publish stamped ----
        unsigned long long* dst = u2_g + (unsigned)(it & 1)*NPTS;
        const unsigned long long hs = ((unsigned long long)(unsigned)(it+1)) << 32;
        const bool last = (it == NITER-1);
        if (idx4 < pn && idx4 < 256) {
            float kv = 0.f, kd = 0.f;
#pragma unroll
            for (int k = 0; k < 13; ++k) {
                if (k < km) {
                    float vj = vbuf[cq[k]];
                    kv = fmaf(Kq[k],  vj, kv);
                    kd = fmaf(Kd2[k], vj, kd);
                }
            }
            kv += __shfl_xor(kv, 1); kv += __shfl_xor(kv, 2);
            float u_new = A / (kv + EPSF);
            if (sub == 0) {
                u_lds[p0 + idx4] = u_new;
                __hip_atomic_store(dst + p0 + idx4,
                                   hs | __float_as_uint(u_new),
                                   __ATOMIC_RELAXED, AGENT);
            }
            if (last) {
                kd += __shfl_xor(kd, 1); kd += __shfl_xor(kd, 2);
                if (sub == 0) li_acc += u_new * kd;
            }
        }
        for (int b2 = 256; b2 < pn; b2 += 256) {   // rare overflow
            int i2 = b2 + idx4;
            if (i2 < pn) {
                int sl = p0 + i2;
                float px = px_l[sl], py = py_l[sl];
                int r_lo, c_lo; window_of(px, py, r_lo, c_lo);
                float kv = 0.f, kd = 0.f;
                for (int q = sub; q < 49; q += 4) {
                    int wy = q / 7, wx = q % 7;
                    float dx = px - (float)(8*(c_lo+wx) + 4);
                    float dy = py - (float)(8*(r_lo+wy) + 4);
                    float d2 = dx*dx + dy*dy;
                    float K = exp2f(C2 * d2);
                    float vj = vbuf[(r_lo + wy - v1lo)*GRID_N + c_lo + wx];
                    kv = fmaf(K, vj, kv); kd = fmaf(K*d2, vj, kd);
                }
                kv += __shfl_xor(kv, 1); kv += __shfl_xor(kv, 2);
                float u_new = A / (kv + EPSF);
                if (sub == 0) {
                    u_lds[sl] = u_new;
                    __hip_atomic_store(dst + sl, hs | __float_as_uint(u_new),
                                       __ATOMIC_RELAXED, AGENT);
                }
                if (last) {
                    kd += __shfl_xor(kd, 1); kd += __shfl_xor(kd, 2);
                    if (sub == 0) li_acc += u_new * kd;
                }
            }
        }
        __syncthreads();
    }

    // ---- loss reduction + last-WG finalize ----
#pragma unroll
    for (int o = 32; o > 0; o >>= 1) li_acc += __shfl_down(li_acc, o);
    if ((t & 63) == 0) red[t >> 6] = li_acc;
    __syncthreads();
    if (t == 0) {
        float s = 0.f;
#pragma unroll
        for (int w = 0; w < 16; ++w) s += red[w];
        atomicAdd(&ws_f[img], s);
        unsigned done = __hip_atomic_fetch_add(ws_u32 + 4, 1u,
                                               __ATOMIC_ACQ_REL, AGENT);
        if (done == (unsigned)(NIMG*NBAND - 1)) {
            float tot = 0.f;
#pragma unroll
            for (int i = 0; i < 4; ++i)
                tot += __hip_atomic_load(ws_f + i, __ATOMIC_RELAXED, AGENT);
            out[0] = tot;
            out[1] = tot;
            out[2] = 0.f;
        }
    }
}

// ---- fallback (ws too small): R1-verified single-kernel path ----
__global__ __launch_bounds__(1024) void ot_fallback_kernel(
    const float* __restrict__ dens, const float* __restrict__ pts,
    float* __restrict__ out)
{
    const int img = blockIdx.x, t = threadIdx.x;
    __shared__ float sv[NCELL];
    __shared__ float redf[16];

    const float px = pts[(size_t)img*NPTS*2 + t*2 + 0];
    const float py = pts[(size_t)img*NPTS*2 + t*2 + 1];
    int r_lo, c_lo; window_of(px, py, r_lo, c_lo);

    float dx2[7], dy2[7];
#pragma unroll
    for (int j = 0; j < 7; ++j) {
        float dx = px - (float)(8*(c_lo+j) + 4);
        float dy = py - (float)(8*(r_lo+j) + 4);
        dx2[j] = dx*dx; dy2[j] = dy*dy;
    }
    float K[49];
#pragma unroll
    for (int wy = 0; wy < 7; ++wy)
#pragma unroll
        for (int wx = 0; wx < 7; ++wx)
            K[wy*7+wx] = exp2f(C2 * (dx2[wx] + dy2[wy]));

    const int lbase = r_lo*GRID_N + c_lo;
    float breg[16];
    const float4* d4 = (const float4*)(dens + (size_t)img*NCELL + t*16);
#pragma unroll
    for (int j = 0; j < 4; ++j) {
        float4 v = d4[j];
        breg[j*4+0]=v.x; breg[j*4+1]=v.y; breg[j*4+2]=v.z; breg[j*4+3]=v.w;
    }
    const float A = 1.0f/(float)NPTS;
    float u = A;
    float4* sv4 = (float4*)sv;
    for (int it = 0; it < NITER; ++it) {
        __syncthreads();
#pragma unroll
        for (int j = 0; j < 4; ++j) sv4[t*4+j] = make_float4(0.f,0.f,0.f,0.f);
        __syncthreads();
#pragma unroll
        for (int wy = 0; wy < 7; ++wy)
#pragma unroll
            for (int wx = 0; wx < 7; ++wx)
                atomicAdd(&sv[lbase + wy*GRID_N + wx], u * K[wy*7+wx]);
        __syncthreads();
#pragma unroll
        for (int j = 0; j < 16; ++j) { int c = t*16+j; sv[c] = breg[j] / (sv[c] + EPSF); }
        __syncthreads();
        float kv = 0.f;
#pragma unroll
        for (int wy = 0; wy < 7; ++wy)
#pragma unroll
            for (int wx = 0; wx < 7; ++wx)
                kv = fmaf(K[wy*7+wx], sv[lbase + wy*GRID_N + wx], kv);
        u = A / (kv + EPSF);
    }
    float li = 0.f;
#pragma unroll
    for (int wy = 0; wy < 7; ++wy)
#pragma unroll
        for (int wx = 0; wx < 7; ++wx)
            li = fmaf(K[wy*7+wx] * (dx2[wx]+dy2[wy]), sv[lbase + wy*GRID_N + wx], li);
    li *= u;
#pragma unroll
    for (int o = 32; o > 0; o >>= 1) li += __shfl_down(li, o);
    if ((t & 63) == 0) redf[t >> 6] = li;
    __syncthreads();
    if (t == 0) {
        float s = 0.f;
#pragma unroll
        for (int w = 0; w < 16; ++w) s += redf[w];
        atomicAdd(&out[0], s);
        atomicAdd(&out[1], s);
    }
}

extern "C" void kernel_launch(void* const* d_in, const int* in_sizes, int n_in,
                              void* d_out, int out_size, void* d_ws, size_t ws_size,
                              hipStream_t stream)
{
    const float* dens = (const float*)d_in[0];   // [4,1,128,128]
    const float* pts  = (const float*)d_in[2];   // [4,1024,2]
    float* out = (float*)d_out;
    unsigned* ws_u32 = (unsigned*)d_ws;

    if (ws_size < (size_t)WS_TOTAL) {   // insurance: slow-but-correct path
        hipMemsetAsync(d_out, 0, 3*sizeof(float), stream);
        ot_fallback_kernel<<<NIMG, 1024, 0, stream>>>(dens, pts, out);
        return;
    }

    hipMemsetAsync(d_ws, 0, ZERO_BYTES, stream);   // loss+done+gate+u2
    ot_main_kernel<<<NIMG*NBAND, TPB, 0, stream>>>(dens, pts, ws_u32, out);
}

// Round 14
// 455.616 us; speedup vs baseline: 1.9367x; 1.0706x over previous
//
#include <hip/hip_runtime.h>

// OT Sinkhorn loss. B=4 images, N=1024 pts, 128x128 grid, 100 iters.
// R14 = R13 + (1) halo-u PREFETCH during phase B (relaxed 8B load; vmcnt
// wait lands at next iter's commit -> LLC latency hidden under compute;
// stamp validated at commit, poll fallback), (2) single combined halo
// index space (1 elem/thread, one LLC RT not two serialized), (3) TWO
// barriers/iter (end-of-loop barrier proven removable: B writes own
// slots only, commit writes halo only -- disjoint; bar1 orders both
// before A'). R13 showed per-iter floor is exposed-LLC + barriers, not
// phase A (R12/R13 both falsified the walk theory).

#define GRID_N 128
#define NCELL  16384
#define NPTS   1024
#define NIMG   4
#define NITER  100
#define STRICT_AT 94
#define SLACK  4
#define NBAND  16
#define TPB    1024
#define VROWS  14
#define VCELLS (VROWS*GRID_N)   // 1792
#define ENT_CAP 12288
#define CPT 2                   // cells/thread in scan (2*1024 >= 1792)

#define C2   (-0.14426950408889634f)   // -log2(e)/10
#define EPSF 1e-16f
#define AGENT __HIP_MEMORY_SCOPE_AGENT

// ws: [0..16) loss f32[4]; [16..20) done; [20..24) gate; [64..) u2 stamps
#define WS_U_B   64
#define WS_TOTAL (WS_U_B + NIMG*2*NPTS*8)
#define ZERO_BYTES WS_TOTAL

__device__ __forceinline__ void window_of(float px, float py, int& r_lo, int& c_lo)
{
    int kc = (int)(px * 0.125f); kc = kc < 0 ? 0 : (kc > GRID_N-1 ? GRID_N-1 : kc);
    int kr = (int)(py * 0.125f); kr = kr < 0 ? 0 : (kr > GRID_N-1 ? GRID_N-1 : kr);
    c_lo = kc - 3; c_lo = c_lo < 0 ? 0 : (c_lo > GRID_N-7 ? GRID_N-7 : c_lo);
    r_lo = kr - 3; r_lo = r_lo < 0 ? 0 : (r_lo > GRID_N-7 ? GRID_N-7 : r_lo);
}

__global__ __launch_bounds__(TPB) void ot_main_kernel(
    const float* __restrict__ dens, const float* __restrict__ pts,
    unsigned* __restrict__ ws_u32, float* __restrict__ out)
{
    const int img = (int)blockIdx.x >> 4, bnd = (int)blockIdx.x & 15;
    const int t = threadIdx.x;
    float* ws_f = (float*)ws_u32;
    unsigned long long* u2_g =
        (unsigned long long*)((char*)ws_u32 + WS_U_B) + img*2*NPTS;

    __shared__ float    vbuf[VCELLS];      // v (aliased cnt during build)
    __shared__ float    densV[VCELLS];
    __shared__ unsigned offs[VCELLS + 1];
    __shared__ unsigned ent[ENT_CAP];      // {K22 | slot10}
    __shared__ float    u_lds[NPTS];       // slot-indexed
    __shared__ float    px_l[NPTS], py_l[NPTS];
    __shared__ unsigned keys_s[NPTS];
    __shared__ unsigned bofs[17];
    __shared__ unsigned cnt16[16];
    __shared__ unsigned swsum[17];
    __shared__ float    red[16];

    const int v1lo = (bnd*8-3) < 0 ? 0 : (bnd*8-3);
    const int v1hi = (bnd*8+10) > 127 ? 127 : (bnd*8+10);
    const int cells = (v1hi - v1lo + 1) * GRID_N;
    const float A = 1.0f / (float)NPTS;

    unsigned* cnt = (unsigned*)vbuf;       // alias during build only

    // ---- init 1: load point, key, band histogram (1 pt/thread) ----
    const float mpx = pts[(img*NPTS + t)*2 + 0];
    const float mpy = pts[(img*NPTS + t)*2 + 1];
    int mkr = (int)(mpy * 0.125f); mkr = mkr < 0 ? 0 : (mkr > 127 ? 127 : mkr);
    const int mband = mkr >> 3;
    const unsigned mkey = ((unsigned)mband << 10) | (unsigned)t;
    keys_s[t] = mkey;
    if (t < 16) cnt16[t] = 0;
    __syncthreads();
    atomicAdd(&cnt16[mband], 1u);
    __syncthreads();
    if (t == 0) {
        unsigned run = 0;
        for (int i = 0; i < 16; ++i) { bofs[i] = run; run += cnt16[i]; }
        bofs[16] = run;
    }
    __syncthreads();

    // ---- init 2: deterministic rank sort (key = band<<10 | pid) ----
    {
        int r = 0;
        for (int q = 0; q < NPTS; ++q) r += (keys_s[q] < mkey);
        px_l[r] = mpx; py_l[r] = mpy; u_lds[r] = A;
    }
    __syncthreads();

    // ---- init 3: densV + zero cnt ----
    for (int i = t; i < cells; i += TPB) {
        densV[i] = dens[img*NCELL + v1lo*GRID_N + i];
        cnt[i] = 0u;
    }
    const int s0 = (int)bofs[bnd > 0 ? bnd-1 : 0];
    const int s1 = (int)bofs[(bnd < 15 ? bnd+1 : 15) + 1];
    const int p0 = (int)bofs[bnd];
    const int pn = (int)bofs[bnd+1] - p0;
    __syncthreads();

    // ---- init 4: local CSR count (points of bands b-1..b+1) ----
    for (int i = s0 + t; i < s1; i += TPB) {
        int r_lo, c_lo; window_of(px_l[i], py_l[i], r_lo, c_lo);
#pragma unroll
        for (int wy = 0; wy < 7; ++wy) {
            int row = r_lo + wy;
            if (row >= v1lo && row <= v1hi) {
                int base = (row - v1lo)*GRID_N + c_lo;
#pragma unroll
                for (int wx = 0; wx < 7; ++wx) atomicAdd(&cnt[base + wx], 1u);
            }
        }
    }
    __syncthreads();

    // ---- init 5: exclusive scan cnt -> offs (16-wave shfl scan) ----
    {
        const int c0 = t*CPT;
        unsigned lc[CPT]; unsigned csum = 0;
#pragma unroll
        for (int k = 0; k < CPT; ++k) {
            int ci = c0 + k;
            lc[k] = (ci < cells) ? cnt[ci] : 0u;
            csum += lc[k];
        }
        unsigned inc = csum;
        const int lane = t & 63;
#pragma unroll
        for (int d = 1; d < 64; d <<= 1) {
            unsigned x = __shfl_up(inc, d, 64);
            if (lane >= d) inc += x;
        }
        if (lane == 63) swsum[t >> 6] = inc;
        __syncthreads();
        if (t < 16) {
            unsigned wv = swsum[t], winc = wv;
#pragma unroll
            for (int d = 1; d < 16; d <<= 1) {
                unsigned x = __shfl_up(winc, d, 16);
                if (t >= d) winc += x;
            }
            swsum[t] = winc - wv;
            if (t == 15) swsum[16] = winc;
        }
        __syncthreads();
        unsigned run = swsum[t >> 6] + (inc - csum);
#pragma unroll
        for (int k = 0; k < CPT; ++k) {
            int ci = c0 + k;
            if (ci < cells) { offs[ci] = run; run += lc[k]; }
        }
        if (t == 0) offs[cells] = swsum[16];
    }
    __syncthreads();

    // ---- init 6: CSR fill {K22|slot10} (drains cnt) ----
    for (int i = s0 + t; i < s1; i += TPB) {
        float px = px_l[i], py = py_l[i];
        int r_lo, c_lo; window_of(px, py, r_lo, c_lo);
#pragma unroll
        for (int wy = 0; wy < 7; ++wy) {
            int row = r_lo + wy;
            if (row >= v1lo && row <= v1hi) {
                float dy = py - (float)(8*row + 4);
                int base = (row - v1lo)*GRID_N + c_lo;
#pragma unroll
                for (int wx = 0; wx < 7; ++wx) {
                    float dx = px - (float)(8*(c_lo+wx) + 4);
                    float K = exp2f(C2 * (dx*dx + dy*dy));
                    unsigned e = ((__float_as_uint(K) + 0x200u) & 0xFFFFFC00u)
                               | (unsigned)i;
                    unsigned old = atomicSub(&cnt[base + wx], 1u);
                    unsigned idx = offs[base + wx] + old - 1u;
                    if (idx < ENT_CAP) ent[idx] = e;
                }
            }
        }
    }
    __syncthreads();

    // ---- init 6.5: cell-side registers (2 cells/thread, stride TPB) ----
    const int ci0 = t, ci1 = t + TPB;
    const bool has1 = (ci1 < cells);
    unsigned ea0 = offs[ci0], eb0 = offs[ci0+1];
    if (eb0 > ENT_CAP) eb0 = ENT_CAP;
    if (ea0 > eb0) ea0 = eb0;
    const float dn0 = densV[ci0];
    unsigned ea1 = 0, eb1 = 0; float dn1 = 0.f;
    if (has1) {
        ea1 = offs[ci1]; eb1 = offs[ci1+1];
        if (eb1 > ENT_CAP) eb1 = ENT_CAP;
        if (ea1 > eb1) ea1 = eb1;
        dn1 = densV[ci1];
    }
    const unsigned n0 = eb0 - ea0, n1 = eb1 - ea1;
    const unsigned nmax = n0 > n1 ? n0 : n1;

    // ---- init 7: prestored K for own points (4 threads/point) ----
    const int sub = t & 3, idx4 = t >> 2;
    int km = 0;
    float Kq[13], Kd2[13]; int cq[13];
    if (idx4 < pn && idx4 < 256) {
        float px = px_l[p0 + idx4], py = py_l[p0 + idx4];
        int r_lo, c_lo; window_of(px, py, r_lo, c_lo);
        int k = 0;
#pragma unroll
        for (int q = 0; q < 49; ++q) {
            if ((q & 3) == sub) {
                int wy = q / 7, wx = q % 7;
                float dx = px - (float)(8*(c_lo+wx) + 4);
                float dy = py - (float)(8*(r_lo+wy) + 4);
                float d2 = dx*dx + dy*dy;
                float K = exp2f(C2 * d2);
                Kq[k] = K; Kd2[k] = K * d2;
                cq[k] = (r_lo + wy - v1lo)*GRID_N + (c_lo + wx);
                ++k;
            }
        }
        km = k;
    }

    // ---- combined halo index space: 1 element/thread ----
    const int nlo = p0 - s0;
    const int nh  = nlo + (s1 - p0 - pn);       // <= 1024
    const int hsl = (t < nlo) ? (s0 + t) : (p0 + pn + (t - nlo));
    const bool hactive = (t < nh);

    // ---- init 8: seed both parity buffers with {stamp0, A}; global gate ----
    for (int i = p0 + t; i < p0 + pn; i += TPB) {
        unsigned long long seed = (unsigned long long)__float_as_uint(A);
        __hip_atomic_store(u2_g + i,        seed, __ATOMIC_RELAXED, AGENT);
        __hip_atomic_store(u2_g + NPTS + i, seed, __ATOMIC_RELAXED, AGENT);
    }
    __syncthreads();
    if (t == 0) {
        __hip_atomic_fetch_add(ws_u32 + 5, 1u, __ATOMIC_ACQ_REL, AGENT);
        int spins = 0;
        while (__hip_atomic_load(ws_u32 + 5, __ATOMIC_ACQUIRE, AGENT)
               < (unsigned)(NIMG*NBAND)) {
            __builtin_amdgcn_s_sleep(2);
            if (++spins > (1<<22)) break;
        }
    }
    __syncthreads();

    float li_acc = 0.f;
    unsigned long long pref_w = 0;   // prefetched halo word (stamp|u)

    // ======== iteration loop: 2 barriers/iter; prefetch hides LLC ========
    for (int it = 0; it < NITER; ++it) {
        // ---- commit halo u^{it-1} (prefetched in prev B; poll if stale) ----
        if (it > 0 && hactive) {
            const int tgt = (it >= STRICT_AT) ? it
                          : (it > SLACK ? it - SLACK : 0);
            unsigned long long w = pref_w;
            if ((int)(unsigned)(w >> 32) < tgt) {
                const unsigned long long* ap =
                    u2_g + (unsigned)((it-1) & 1)*NPTS + hsl;
                int spins = 0;
                w = __hip_atomic_load(ap, __ATOMIC_RELAXED, AGENT);
                while ((int)(unsigned)(w >> 32) < tgt) {
                    __builtin_amdgcn_s_sleep(1);
                    w = __hip_atomic_load(ap, __ATOMIC_RELAXED, AGENT);
                    if (++spins > (1<<22)) break;   // monotone => unreachable
                }
            }
            u_lds[hsl] = __uint_as_float((unsigned)w);
        }
        __syncthreads();   // bar1: u_lds (halo commit + prev B own) ready

        // ---- phase A: interleaved affine 2-cell walk, 2-way ILP ----
        {
            float sum0 = 0.f, sum1 = 0.f;
            for (unsigned k = 0; k < nmax; ++k) {
                if (k < n0) {
                    unsigned E = ent[ea0 + k];
                    sum0 = fmaf(__uint_as_float(E & 0xFFFFFC00u),
                                u_lds[E & 0x3FFu], sum0);
                }
                if (k < n1) {
                    unsigned E = ent[ea1 + k];
                    sum1 = fmaf(__uint_as_float(E & 0xFFFFFC00u),
                                u_lds[E & 0x3FFu], sum1);
                }
            }
            vbuf[ci0] = dn0 / (sum0 + EPSF);
            if (has1) vbuf[ci1] = dn1 / (sum1 + EPSF);
        }
        __syncthreads();   // bar2: vbuf ready for B

        // ---- phase B: u = A/(K v + eps); publish; prefetch next halo ----
        unsigned long long* dst = u2_g + (unsigned)(it & 1)*NPTS;
        const unsigned long long hs = ((unsigned long long)(unsigned)(it+1)) << 32;
        const bool last = (it == NITER-1);
        if (idx4 < pn && idx4 < 256) {
            float kv = 0.f, kd = 0.f;
#pragma unroll
            for (int k = 0; k < 13; ++k) {
                if (k < km) {
                    float vj = vbuf[cq[k]];
                    kv = fmaf(Kq[k],  vj, kv);
                    kd = fmaf(Kd2[k], vj, kd);
                }
            }
            kv += __shfl_xor(kv, 1); kv += __shfl_xor(kv, 2);
            float u_new = A / (kv + EPSF);
            if (sub == 0) {
                u_lds[p0 + idx4] = u_new;
                __hip_atomic_store(dst + p0 + idx4,
                                   hs | __float_as_uint(u_new),
                                   __ATOMIC_RELAXED, AGENT);
            }
            if (last) {
                kd += __shfl_xor(kd, 1); kd += __shfl_xor(kd, 2);
                if (sub == 0) li_acc += u_new * kd;
            }
        }
        for (int b2 = 256; b2 < pn; b2 += 256) {   // rare overflow
            int i2 = b2 + idx4;
            if (i2 < pn) {
                int sl = p0 + i2;
                float px = px_l[sl], py = py_l[sl];
                int r_lo, c_lo; window_of(px, py, r_lo, c_lo);
                float kv = 0.f, kd = 0.f;
                for (int q = sub; q < 49; q += 4) {
                    int wy = q / 7, wx = q % 7;
                    float dx = px - (float)(8*(c_lo+wx) + 4);
                    float dy = py - (float)(8*(r_lo+wy) + 4);
                    float d2 = dx*dx + dy*dy;
                    float K = exp2f(C2 * d2);
                    float vj = vbuf[(r_lo + wy - v1lo)*GRID_N + c_lo + wx];
                    kv = fmaf(K, vj, kv); kd = fmaf(K*d2, vj, kd);
                }
                kv += __shfl_xor(kv, 1); kv += __shfl_xor(kv, 2);
                float u_new = A / (kv + EPSF);
                if (sub == 0) {
                    u_lds[sl] = u_new;
                    __hip_atomic_store(dst + sl, hs | __float_as_uint(u_new),
                                       __ATOMIC_RELAXED, AGENT);
                }
                if (last) {
                    kd += __shfl_xor(kd, 1); kd += __shfl_xor(kd, 2);
                    if (sub == 0) li_acc += u_new * kd;
                }
            }
        }
        // prefetch next-iter halo word (parity it&1); consumed at commit
        if (hactive)
            pref_w = __hip_atomic_load(u2_g + (unsigned)(it & 1)*NPTS + hsl,
                                       __ATOMIC_RELAXED, AGENT);
        // NO end-of-loop barrier: B writes own slots, next commit writes
        // halo slots (disjoint); bar1 orders both before next A.
    }

    // ---- loss reduction + last-WG finalize ----
#pragma unroll
    for (int o = 32; o > 0; o >>= 1) li_acc += __shfl_down(li_acc, o);
    if ((t & 63) == 0) red[t >> 6] = li_acc;
    __syncthreads();
    if (t == 0) {
        float s = 0.f;
#pragma unroll
        for (int w = 0; w < 16; ++w) s += red[w];
        atomicAdd(&ws_f[img], s);
        unsigned done = __hip_atomic_fetch_add(ws_u32 + 4, 1u,
                                               __ATOMIC_ACQ_REL, AGENT);
        if (done == (unsigned)(NIMG*NBAND - 1)) {
            float tot = 0.f;
#pragma unroll
            for (int i = 0; i < 4; ++i)
                tot += __hip_atomic_load(ws_f + i, __ATOMIC_RELAXED, AGENT);
            out[0] = tot;
            out[1] = tot;
            out[2] = 0.f;
        }
    }
}

// ---- fallback (ws too small): R1-verified single-kernel path ----
__global__ __launch_bounds__(1024) void ot_fallback_kernel(
    const float* __restrict__ dens, const float* __restrict__ pts,
    float* __restrict__ out)
{
    const int img = blockIdx.x, t = threadIdx.x;
    __shared__ float sv[NCELL];
    __shared__ float redf[16];

    const float px = pts[(size_t)img*NPTS*2 + t*2 + 0];
    const float py = pts[(size_t)img*NPTS*2 + t*2 + 1];
    int r_lo, c_lo; window_of(px, py, r_lo, c_lo);

    float dx2[7], dy2[7];
#pragma unroll
    for (int j = 0; j < 7; ++j) {
        float dx = px - (float)(8*(c_lo+j) + 4);
        float dy = py - (float)(8*(r_lo+j) + 4);
        dx2[j] = dx*dx; dy2[j] = dy*dy;
    }
    float K[49];
#pragma unroll
    for (int wy = 0; wy < 7; ++wy)
#pragma unroll
        for (int wx = 0; wx < 7; ++wx)
            K[wy*7+wx] = exp2f(C2 * (dx2[wx] + dy2[wy]));

    const int lbase = r_lo*GRID_N + c_lo;
    float breg[16];
    const float4* d4 = (const float4*)(dens + (size_t)img*NCELL + t*16);
#pragma unroll
    for (int j = 0; j < 4; ++j) {
        float4 v = d4[j];
        breg[j*4+0]=v.x; breg[j*4+1]=v.y; breg[j*4+2]=v.z; breg[j*4+3]=v.w;
    }
    const float A = 1.0f/(float)NPTS;
    float u = A;
    float4* sv4 = (float4*)sv;
    for (int it = 0; it < NITER; ++it) {
        __syncthreads();
#pragma unroll
        for (int j = 0; j < 4; ++j) sv4[t*4+j] = make_float4(0.f,0.f,0.f,0.f);
        __syncthreads();
#pragma unroll
        for (int wy = 0; wy < 7; ++wy)
#pragma unroll
            for (int wx = 0; wx < 7; ++wx)
                atomicAdd(&sv[lbase + wy*GRID_N + wx], u * K[wy*7+wx]);
        __syncthreads();
#pragma unroll
        for (int j = 0; j < 16; ++j) { int c = t*16+j; sv[c] = breg[j] / (sv[c] + EPSF); }
        __syncthreads();
        float kv = 0.f;
#pragma unroll
        for (int wy = 0; wy < 7; ++wy)
#pragma unroll
            for (int wx = 0; wx < 7; ++wx)
                kv = fmaf(K[wy*7+wx], sv[lbase + wy*GRID_N + wx], kv);
        u = A / (kv + EPSF);
    }
    float li = 0.f;
#pragma unroll
    for (int wy = 0; wy < 7; ++wy)
#pragma unroll
        for (int wx = 0; wx < 7; ++wx)
            li = fmaf(K[wy*7+wx] * (dx2[wx]+dy2[wy]), sv[lbase + wy*GRID_N + wx], li);
    li *= u;
#pragma unroll
    for (int o = 32; o > 0; o >>= 1) li += __shfl_down(li, o);
    if ((t & 63) == 0) redf[t >> 6] = li;
    __syncthreads();
    if (t == 0) {
        float s = 0.f;
#pragma unroll
        for (int w = 0; w < 16; ++w) s += redf[w];
        atomicAdd(&out[0], s);
        atomicAdd(&out[1], s);
    }
}

extern "C" void kernel_launch(void* const* d_in, const int* in_sizes, int n_in,
                              void* d_out, int out_size, void* d_ws, size_t ws_size,
                              hipStream_t stream)
{
    const float* dens = (const float*)d_in[0];   // [4,1,128,128]
    const float* pts  = (const float*)d_in[2];   // [4,1024,2]
    float* out = (float*)d_out;
    unsigned* ws_u32 = (unsigned*)d_ws;

    if (ws_size < (size_t)WS_TOTAL) {   // insurance: slow-but-correct path
        hipMemsetAsync(d_out, 0, 3*sizeof(float), stream);
        ot_fallback_kernel<<<NIMG, 1024, 0, stream>>>(dens, pts, out);
        return;
    }

    hipMemsetAsync(d_ws, 0, ZERO_BYTES, stream);   // loss+done+gate+u2
    ot_main_kernel<<<NIMG*NBAND, TPB, 0, stream>>>(dens, pts, ws_u32, out);
}